// Round 13
// baseline (1196.067 us; speedup 1.0000x reference)
//
#include <hip/hip_runtime.h>
#include <math.h>

#define N_NODES 50000
#define N_EDGES 800000
#define D_IN 256
#define D_HID 128
#define ALPHA 0.1f
#define EPS 1e-5f

#define NBUCK 391   // ceil(50000/128)
#define EPB 4096    // edges per histogram/scatter block
#define NBLK 196    // ceil(800000/4096)

typedef __attribute__((ext_vector_type(8))) short bf16x8;
typedef __attribute__((ext_vector_type(4))) float f32x4;

static __device__ __forceinline__ unsigned short f2bf(float f) {
    unsigned int x = __float_as_uint(f);
    return (unsigned short)((x + 0x7fffu + ((x >> 16) & 1u)) >> 16);
}
static __device__ __forceinline__ float blo(unsigned int v) {
    return __uint_as_float(v << 16);
}
static __device__ __forceinline__ float bhi(unsigned int v) {
    return __uint_as_float(v & 0xffff0000u);
}
static __device__ __forceinline__ void unpack8(uint4 u, float* f) {
    f[0] = blo(u.x); f[1] = bhi(u.x);
    f[2] = blo(u.y); f[3] = bhi(u.y);
    f[4] = blo(u.z); f[5] = bhi(u.z);
    f[6] = blo(u.w); f[7] = bhi(u.w);
}

// ---------------- CSR build: hierarchical counting sort ----------------
__global__ __launch_bounds__(256) void k_hist(const int* __restrict__ dst,
                                              int* __restrict__ hist, int e) {
    __shared__ int h[NBUCK];
    int t = threadIdx.x;
    for (int i = t; i < NBUCK; i += 256) h[i] = 0;
    __syncthreads();
    int base = blockIdx.x * EPB;
    int lim = e - base;
    if (lim > EPB) lim = EPB;
    for (int i = t; i < lim; i += 256) atomicAdd(&h[dst[base + i] >> 7], 1);
    __syncthreads();
    for (int i = t; i < NBUCK; i += 256) hist[blockIdx.x * NBUCK + i] = h[i];
}

__global__ __launch_bounds__(256) void k_bkscan(const int* __restrict__ hist,
                                                int* __restrict__ offsT, int* __restrict__ btot) {
    __shared__ int sh[256];
    int b = blockIdx.x;
    int t = threadIdx.x;
    int v = (t < NBLK) ? hist[t * NBUCK + b] : 0;
    sh[t] = v;
    __syncthreads();
    for (int ofs = 1; ofs < 256; ofs <<= 1) {
        int y = (t >= ofs) ? sh[t - ofs] : 0;
        __syncthreads();
        sh[t] += y;
        __syncthreads();
    }
    if (t < NBLK) offsT[b * NBLK + t] = sh[t] - v;
    if (t == 255) btot[b] = sh[255];
}

__global__ __launch_bounds__(512) void k_bbase(const int* __restrict__ btot,
                                               int* __restrict__ bbase, int* __restrict__ rp) {
    __shared__ int sh[512];
    int t = threadIdx.x;
    int v = (t < NBUCK) ? btot[t] : 0;
    sh[t] = v;
    __syncthreads();
    for (int ofs = 1; ofs < 512; ofs <<= 1) {
        int y = (t >= ofs) ? sh[t - ofs] : 0;
        __syncthreads();
        sh[t] += y;
        __syncthreads();
    }
    if (t < NBUCK) bbase[t] = sh[t] - v;
    if (t == 0) rp[N_NODES] = N_EDGES;
}

__global__ __launch_bounds__(256) void k_scatter(const int* __restrict__ src,
                                                 const int* __restrict__ dst,
                                                 const int* __restrict__ offsT,
                                                 const int* __restrict__ bbase,
                                                 unsigned int* __restrict__ buck, int e) {
    __shared__ int h[NBUCK];
    int t = threadIdx.x;
    for (int i = t; i < NBUCK; i += 256) h[i] = 0;
    __syncthreads();
    int base = blockIdx.x * EPB;
    int lim = e - base;
    if (lim > EPB) lim = EPB;
    for (int i = t; i < lim; i += 256) {
        int d = dst[base + i];
        int s = src[base + i];
        int b = d >> 7;
        int lp = atomicAdd(&h[b], 1);
        int pos = bbase[b] + offsT[b * NBLK + blockIdx.x] + lp;
        buck[pos] = (unsigned int)s | ((unsigned int)(d & 127) << 16);
    }
}

// cs written as ushort (node ids < 65536)
__global__ __launch_bounds__(256) void k_csr(const unsigned int* __restrict__ buck,
                                             const int* __restrict__ bbase,
                                             const int* __restrict__ btot,
                                             int* __restrict__ rp, float* __restrict__ dinv,
                                             unsigned short* __restrict__ cs) {
    __shared__ int dcnt[128];
    __shared__ int doff[128];
    int b = blockIdx.x;
    int t = threadIdx.x;
    if (t < 128) dcnt[t] = 0;
    __syncthreads();
    int base = bbase[b];
    int tot = btot[b];
    for (int i = t; i < tot; i += 256) {
        unsigned int v = buck[base + i];
        atomicAdd(&dcnt[(v >> 16) & 127], 1);
    }
    __syncthreads();
    if (t < 128) doff[t] = dcnt[t];
    __syncthreads();
    for (int ofs = 1; ofs < 128; ofs <<= 1) {
        int y = 0;
        if (t < 128 && t >= ofs) y = doff[t - ofs];
        __syncthreads();
        if (t < 128) doff[t] += y;
        __syncthreads();
    }
    int gd0 = b << 7;
    if (t < 128) {
        int ex = doff[t] - dcnt[t];
        if (gd0 + t < N_NODES) {
            rp[gd0 + t] = base + ex;
            dinv[gd0 + t] = rsqrtf((float)(dcnt[t] + 1));
        }
        dcnt[t] = ex;
    }
    __syncthreads();
    for (int i = t; i < tot; i += 256) {
        unsigned int v = buck[base + i];
        int p = atomicAdd(&dcnt[(v >> 16) & 127], 1);
        cs[base + p] = (unsigned short)(v & 0xffffu);
    }
}

// ---------------- cast x to bf16 (streaming, full occupancy) ----------------
__global__ __launch_bounds__(256) void k_cast_x(const float4* __restrict__ x, ushort2* __restrict__ xb,
                                                int n4) {
    int i = blockIdx.x * 256 + threadIdx.x;
    if (i < n4) {
        float4 v = x[i];
        ushort2 a;
        a.x = f2bf(v.x); a.y = f2bf(v.y);
        ushort2 b;
        b.x = f2bf(v.z); b.y = f2bf(v.w);
        xb[i * 2] = a;
        xb[i * 2 + 1] = b;
    }
}

// ---------------- prep weights ----------------
__global__ __launch_bounds__(256) void k_prep_w(const float* __restrict__ W_lin,
                                                const float* __restrict__ W1s,
                                                unsigned short* __restrict__ Wlt,
                                                unsigned short* __restrict__ Wt) {
    int idx = blockIdx.x * 256 + threadIdx.x;
    if (idx < 128 * 256) {
        int c = idx >> 8, k = idx & 255;
        Wlt[idx] = f2bf(W_lin[k * 128 + c]);
    } else {
        int j = idx - 128 * 256;
        if (j < 5 * 128 * 128) {
            int l = j >> 14;
            int rem = j & 16383;
            int c = rem >> 7, k = rem & 127;
            float bet = logf(0.5f / (float)(l + 1) + 1.0f);
            float v = bet * W1s[l * 16384 + k * 128 + c];
            if (c == k) v += 1.0f - bet;
            Wt[j] = f2bf(v);
        }
    }
}

// ---------------- first GEMM (K=256): A row-major bf16 -> out plane-major bf16 ----------------
// Plane-major: plane p (cols 16p..16p+15) stored as [N][32B]; uint4 index ((p*N + row)*2 + c).
template <int K>
__global__ __launch_bounds__(256) void k_mgemm(const unsigned short* __restrict__ A,
                                               const unsigned short* __restrict__ Bt,
                                               uint4* __restrict__ outp, int M) {
    __shared__ short lds[2 * 128 * 136];
    short* As = lds;
    short* Bs = lds + 128 * 136;

    int t = threadIdx.x;
    int lane = t & 63;
    int wave = t >> 6;
    int wr = wave >> 1, wc = wave & 1;
    int row0 = blockIdx.x * 128;

    f32x4 acc[4][4];
#pragma unroll
    for (int m = 0; m < 4; ++m)
#pragma unroll
        for (int n = 0; n < 4; ++n) acc[m][n] = (f32x4){0.f, 0.f, 0.f, 0.f};

    int sr = t >> 1;
    int sh = t & 1;

    for (int k0 = 0; k0 < K; k0 += 128) {
        {
            int gr = row0 + sr;
            uint4 zero = {0, 0, 0, 0};
            const uint4* gp = (const uint4*)(A + (size_t)gr * K + k0 + sh * 64);
#pragma unroll
            for (int u = 0; u < 8; ++u) {
                uint4 v = (gr < M) ? gp[u] : zero;
                *(uint4*)(As + sr * 136 + sh * 64 + u * 8) = v;
            }
        }
        {
            const uint4* gp = (const uint4*)(Bt + (size_t)sr * K + k0 + sh * 64);
#pragma unroll
            for (int u = 0; u < 8; ++u) {
                *(uint4*)(Bs + sr * 136 + sh * 64 + u * 8) = gp[u];
            }
        }
        __syncthreads();

#pragma unroll
        for (int ks = 0; ks < 4; ++ks) {
            bf16x8 af[4], bfr[4];
#pragma unroll
            for (int m = 0; m < 4; ++m)
                af[m] = *(const bf16x8*)(As + (wr * 64 + m * 16 + (lane & 15)) * 136 + ks * 32 + (lane >> 4) * 8);
#pragma unroll
            for (int n = 0; n < 4; ++n)
                bfr[n] = *(const bf16x8*)(Bs + (wc * 64 + n * 16 + (lane & 15)) * 136 + ks * 32 + (lane >> 4) * 8);
#pragma unroll
            for (int m = 0; m < 4; ++m)
#pragma unroll
                for (int n = 0; n < 4; ++n)
                    acc[m][n] = __builtin_amdgcn_mfma_f32_16x16x32_bf16(af[m], bfr[n], acc[m][n], 0, 0, 0);
        }
        __syncthreads();
    }

    short* Z = lds;
#pragma unroll
    for (int m = 0; m < 4; ++m)
#pragma unroll
        for (int n = 0; n < 4; ++n)
#pragma unroll
            for (int r = 0; r < 4; ++r) {
                int rl = wr * 64 + m * 16 + (lane >> 4) * 4 + r;
                int cl = wc * 64 + n * 16 + (lane & 15);
                Z[rl * 136 + cl] = (short)f2bf(acc[m][n][r]);
            }
    __syncthreads();
    int rr = t >> 1, cc = t & 1;
    int gr = row0 + rr;
    if (gr < M) {
#pragma unroll
        for (int p = 0; p < 8; ++p)
            outp[((size_t)p * M + gr) * 2 + cc] = *(uint4*)(Z + rr * 136 + p * 16 + cc * 8);
    }
}

// ---------------- layer GEMM (K=128): A plane-major, B in registers ----------------
// MODE 1: plane-major bf16 out + BN stats; MODE 2: f32 row-major out
template <int MODE>
__global__ __launch_bounds__(256) void k_lgemm(const uint4* __restrict__ Ap,
                                               const unsigned short* __restrict__ Bt,
                                               uint4* __restrict__ outp,
                                               float* __restrict__ outf,
                                               float* __restrict__ bn_s, float* __restrict__ bn_q,
                                               int M) {
    __shared__ short As[128 * 136];
    int t = threadIdx.x;
    int lane = t & 63;
    int wave = t >> 6;
    int wr = wave >> 1, wc = wave & 1;
    int row0 = blockIdx.x * 128;

    bf16x8 bfr[4][4];
#pragma unroll
    for (int ks = 0; ks < 4; ++ks)
#pragma unroll
        for (int n = 0; n < 4; ++n)
            bfr[ks][n] = *(const bf16x8*)(Bt + (size_t)(wc * 64 + n * 16 + (lane & 15)) * 128 + ks * 32 + (lane >> 4) * 8);

    // stage A from 8 planes
    {
        int rr = t >> 1, cc = t & 1;
        int gr = row0 + rr;
        uint4 zero = {0, 0, 0, 0};
#pragma unroll
        for (int p = 0; p < 8; ++p) {
            uint4 v = (gr < M) ? Ap[((size_t)p * M + gr) * 2 + cc] : zero;
            *(uint4*)(As + rr * 136 + p * 16 + cc * 8) = v;
        }
    }
    __syncthreads();

    f32x4 acc[4][4];
#pragma unroll
    for (int m = 0; m < 4; ++m)
#pragma unroll
        for (int n = 0; n < 4; ++n) acc[m][n] = (f32x4){0.f, 0.f, 0.f, 0.f};

#pragma unroll
    for (int ks = 0; ks < 4; ++ks) {
        bf16x8 af[4];
#pragma unroll
        for (int m = 0; m < 4; ++m)
            af[m] = *(const bf16x8*)(As + (wr * 64 + m * 16 + (lane & 15)) * 136 + ks * 32 + (lane >> 4) * 8);
#pragma unroll
        for (int m = 0; m < 4; ++m)
#pragma unroll
            for (int n = 0; n < 4; ++n)
                acc[m][n] = __builtin_amdgcn_mfma_f32_16x16x32_bf16(af[m], bfr[ks][n], acc[m][n], 0, 0, 0);
    }

    if (MODE == 1) {
        float sum[4] = {0.f, 0.f, 0.f, 0.f}, sq[4] = {0.f, 0.f, 0.f, 0.f};
#pragma unroll
        for (int n = 0; n < 4; ++n)
#pragma unroll
            for (int m = 0; m < 4; ++m)
#pragma unroll
                for (int r = 0; r < 4; ++r) {
                    float v = acc[m][n][r];
                    sum[n] += v;
                    sq[n] += v * v;
                }
#pragma unroll
        for (int n = 0; n < 4; ++n) {
            sum[n] += __shfl_xor(sum[n], 16);
            sum[n] += __shfl_xor(sum[n], 32);
            sq[n] += __shfl_xor(sq[n], 16);
            sq[n] += __shfl_xor(sq[n], 32);
        }
        if (lane < 16) {
#pragma unroll
            for (int n = 0; n < 4; ++n) {
                int col = wc * 64 + n * 16 + lane;
                atomicAdd(&bn_s[col], sum[n]);
                atomicAdd(&bn_q[col], sq[n]);
            }
        }
    }

    if (MODE == 2) {
#pragma unroll
        for (int m = 0; m < 4; ++m)
#pragma unroll
            for (int n = 0; n < 4; ++n)
#pragma unroll
                for (int r = 0; r < 4; ++r) {
                    int gr = row0 + wr * 64 + m * 16 + (lane >> 4) * 4 + r;
                    int cl = wc * 64 + n * 16 + (lane & 15);
                    if (gr < M) outf[(size_t)gr * 128 + cl] = acc[m][n][r];
                }
    } else {
        __syncthreads();
        short* Z = As;
#pragma unroll
        for (int m = 0; m < 4; ++m)
#pragma unroll
            for (int n = 0; n < 4; ++n)
#pragma unroll
                for (int r = 0; r < 4; ++r) {
                    int rl = wr * 64 + m * 16 + (lane >> 4) * 4 + r;
                    int cl = wc * 64 + n * 16 + (lane & 15);
                    Z[rl * 136 + cl] = (short)f2bf(acc[m][n][r]);
                }
        __syncthreads();
        int rr = t >> 1, cc = t & 1;
        int gr = row0 + rr;
        if (gr < M) {
#pragma unroll
            for (int p = 0; p < 8; ++p)
                outp[((size_t)p * M + gr) * 2 + cc] = *(uint4*)(Z + rr * 136 + p * 16 + cc * 8);
        }
    }
}

// ---------------- aggregation: plane-sliced across XCDs ----------------
// slice = bid & 7 -> XCD via round-robin; per XCD the touched plane is 1.6 MB (L2-resident).
// Block 256 thr = 4 waves = 4 nodes. Wave: lane = 2*q + c; edge slot q (0..31), 16B chunk c.
// MODE 0: GCNConv; MODE 1: GCN2 plain; MODE 2: GCN2 + fused BN/ReLU
template <int MODE>
__global__ __launch_bounds__(256) void k_agg(const uint4* __restrict__ srcp,
                                             const uint4* __restrict__ x0p,
                                             const int* __restrict__ rp,
                                             const unsigned short* __restrict__ cs,
                                             const float* __restrict__ dinv,
                                             const float* __restrict__ b_lin,
                                             const float* __restrict__ st,
                                             uint4* __restrict__ dstp,
                                             float* __restrict__ bns, int n) {
    if (blockIdx.x == 0) bns[threadIdx.x] = 0.f;  // zero BN stats for the following GEMM

    int slice = blockIdx.x & 7;
    int node = (blockIdx.x >> 3) * 4 + (threadIdx.x >> 6);
    if (node >= n) return;
    int lane = threadIdx.x & 63;
    int q = lane >> 1;            // edge slot 0..31
    int c = lane & 1;             // 16B chunk within 32B slice row

    int start = __builtin_amdgcn_readfirstlane(rp[node]);
    int end = __builtin_amdgcn_readfirstlane(rp[node + 1]);

    float sc[8], tc[8];
    if (MODE == 2) {
        float4 s0 = ((const float4*)st)[slice * 4 + c * 2];
        float4 s1 = ((const float4*)st)[slice * 4 + c * 2 + 1];
        float4 t0 = ((const float4*)st)[32 + slice * 4 + c * 2];
        float4 t1 = ((const float4*)st)[32 + slice * 4 + c * 2 + 1];
        sc[0] = s0.x; sc[1] = s0.y; sc[2] = s0.z; sc[3] = s0.w;
        sc[4] = s1.x; sc[5] = s1.y; sc[6] = s1.z; sc[7] = s1.w;
        tc[0] = t0.x; tc[1] = t0.y; tc[2] = t0.z; tc[3] = t0.w;
        tc[4] = t1.x; tc[5] = t1.y; tc[6] = t1.z; tc[7] = t1.w;
    }
    float dn = (MODE == 0) ? dinv[node] : 0.f;
    size_t pbase = (size_t)slice * n;

    float acc[8];
#pragma unroll
    for (int i = 0; i < 8; ++i) acc[i] = 0.f;

#define ACCW(vv, ww)                                                       \
    {                                                                      \
        float f_[8];                                                       \
        unpack8(vv, f_);                                                   \
        if (MODE == 2) {                                                   \
            _Pragma("unroll") for (int i_ = 0; i_ < 8; ++i_)               \
                acc[i_] = fmaf(ww, fmaxf(fmaf(sc[i_], f_[i_], tc[i_]), 0.f), acc[i_]); \
        } else {                                                           \
            _Pragma("unroll") for (int i_ = 0; i_ < 8; ++i_)               \
                acc[i_] = fmaf(ww, f_[i_], acc[i_]);                       \
        }                                                                  \
    }
#define ACCP(vv)                                                           \
    {                                                                      \
        float f_[8];                                                       \
        unpack8(vv, f_);                                                   \
        if (MODE == 2) {                                                   \
            _Pragma("unroll") for (int i_ = 0; i_ < 8; ++i_)               \
                acc[i_] += fmaxf(fmaf(sc[i_], f_[i_], tc[i_]), 0.f);       \
        } else {                                                           \
            _Pragma("unroll") for (int i_ = 0; i_ < 8; ++i_)               \
                acc[i_] += f_[i_];                                         \
        }                                                                  \
    }

    for (int base = start; base < end; base += 64) {
        int cnt = end - base;
        if (cnt > 64) cnt = 64;
        int li = (lane < cnt) ? lane : (cnt - 1);
        int myi = (int)cs[base + li];
        float myw = (MODE == 0) ? dinv[myi] : 0.f;

        for (int j = 0; j < cnt; j += 32) {
            int jj = j + q;
            if (j + 32 <= cnt) {
                int i0 = __shfl(myi, jj);
                uint4 v = srcp[(pbase + i0) * 2 + c];
                if (MODE == 0) {
                    float w = __shfl(myw, jj) * dn;
                    ACCW(v, w);
                } else {
                    ACCP(v);
                }
            } else {
                bool act = jj < cnt;
                int js = act ? jj : (cnt - 1);
                int i0 = __shfl(myi, js);
                uint4 v = srcp[(pbase + i0) * 2 + c];
                float m = act ? 1.f : 0.f;
                float w = (MODE == 0) ? (__shfl(myw, js) * dn * m) : m;
                ACCW(v, w);
            }
        }
    }
#undef ACCW
#undef ACCP

    // fold edge-slots q (lane bits 1..5)
#pragma unroll
    for (int i = 0; i < 8; ++i) {
        acc[i] += __shfl_xor(acc[i], 2);
        acc[i] += __shfl_xor(acc[i], 4);
        acc[i] += __shfl_xor(acc[i], 8);
        acc[i] += __shfl_xor(acc[i], 16);
        acc[i] += __shfl_xor(acc[i], 32);
    }

    if (lane < 2) {
        float res[8];
        if (MODE == 0) {
            uint4 sv = srcp[(pbase + node) * 2 + c];
            float fs[8];
            unpack8(sv, fs);
            float w2 = dn * dn;
            float4 b0 = ((const float4*)b_lin)[slice * 4 + c * 2];
            float4 b1 = ((const float4*)b_lin)[slice * 4 + c * 2 + 1];
            float bb[8] = {b0.x, b0.y, b0.z, b0.w, b1.x, b1.y, b1.z, b1.w};
#pragma unroll
            for (int i = 0; i < 8; ++i) res[i] = fmaf(w2, fs[i], acc[i]) + bb[i];
        } else {
            uint4 xv = x0p[(pbase + node) * 2 + c];
            float fx[8];
            unpack8(xv, fx);
#pragma unroll
            for (int i = 0; i < 8; ++i) res[i] = fmaf(ALPHA, fx[i], (1.0f - ALPHA) * acc[i]);
        }
        uint4 o;
        o.x = (unsigned int)f2bf(res[0]) | ((unsigned int)f2bf(res[1]) << 16);
        o.y = (unsigned int)f2bf(res[2]) | ((unsigned int)f2bf(res[3]) << 16);
        o.z = (unsigned int)f2bf(res[4]) | ((unsigned int)f2bf(res[5]) << 16);
        o.w = (unsigned int)f2bf(res[6]) | ((unsigned int)f2bf(res[7]) << 16);
        dstp[(pbase + node) * 2 + c] = o;
    }
}

// ---------------- BN finalize ----------------
__global__ void k_bn_fin(const float* __restrict__ bn_s, const float* __restrict__ bn_q,
                         const float* __restrict__ gamma, const float* __restrict__ betap,
                         float* __restrict__ st, int n) {
    int c = threadIdx.x;
    float inv_n = 1.0f / (float)n;
    float mu = bn_s[c] * inv_n;
    float var = bn_q[c] * inv_n - mu * mu;
    var = fmaxf(var, 0.f);
    float s = gamma[c] * rsqrtf(var + EPS);
    st[c] = s;
    st[128 + c] = betap[c] - mu * s;
}

extern "C" void kernel_launch(void* const* d_in, const int* in_sizes, int n_in,
                              void* d_out, int out_size, void* d_ws, size_t ws_size,
                              hipStream_t stream) {
    const float* x = (const float*)d_in[0];
    const int* ei = (const int*)d_in[1];
    const float* W_lin = (const float*)d_in[2];
    const float* b_lin = (const float*)d_in[3];
    const float* W1s = (const float*)d_in[4];
    const float* gam = (const float*)d_in[5];
    const float* betp = (const float*)d_in[6];
    float* out = (float*)d_out;

    char* ws = (char*)d_ws;
    size_t off = 0;
    auto alloc = [&](size_t b) { size_t p = off; off = (off + b + 255) & ~(size_t)255; return p; };
    int* rp = (int*)(ws + alloc((size_t)(N_NODES + 1) * 4));
    unsigned short* cs = (unsigned short*)(ws + alloc((size_t)N_EDGES * 2));
    float* dinv = (float*)(ws + alloc((size_t)N_NODES * 4));
    int* hist = (int*)(ws + alloc((size_t)NBLK * NBUCK * 4));
    int* offsT = (int*)(ws + alloc((size_t)NBUCK * NBLK * 4));
    int* btot = (int*)(ws + alloc((size_t)NBUCK * 4));
    int* bbase = (int*)(ws + alloc((size_t)NBUCK * 4));
    unsigned int* buck = (unsigned int*)(ws + alloc((size_t)N_EDGES * 4));
    unsigned short* xb = (unsigned short*)(ws + alloc((size_t)N_NODES * D_IN * 2));
    uint4* xwp = (uint4*)(ws + alloc((size_t)N_NODES * D_HID * 2));
    uint4* x0p = (uint4*)(ws + alloc((size_t)N_NODES * D_HID * 2));
    uint4* zp = (uint4*)(ws + alloc((size_t)N_NODES * D_HID * 2));
    uint4* hp = (uint4*)(ws + alloc((size_t)N_NODES * D_HID * 2));
    unsigned short* Wlt = (unsigned short*)(ws + alloc((size_t)128 * 256 * 2));
    unsigned short* Wt = (unsigned short*)(ws + alloc((size_t)5 * 128 * 128 * 2));
    float* bns = (float*)(ws + alloc(256 * 4));
    float* st = (float*)(ws + alloc(256 * 4));

    const int ggrid = (N_NODES + 127) / 128;          // 391
    const int agrid = ((N_NODES + 3) / 4) * 8;        // 100000 (node-chunk x slice)

    // CSR build (counting sort, coalesced writes)
    k_hist<<<NBLK, 256, 0, stream>>>(ei + N_EDGES, hist, N_EDGES);
    k_bkscan<<<NBUCK, 256, 0, stream>>>(hist, offsT, btot);
    k_bbase<<<1, 512, 0, stream>>>(btot, bbase, rp);
    k_scatter<<<NBLK, 256, 0, stream>>>(ei, ei + N_EDGES, offsT, bbase, buck, N_EDGES);
    k_csr<<<NBUCK, 256, 0, stream>>>(buck, bbase, btot, rp, dinv, cs);

    k_cast_x<<<(N_NODES * D_IN / 4 + 255) / 256, 256, 0, stream>>>((const float4*)x, (ushort2*)xb,
                                                                   N_NODES * D_IN / 4);
    k_prep_w<<<(128 * 256 + 5 * 128 * 128 + 255) / 256, 256, 0, stream>>>(W_lin, W1s, Wlt, Wt);

    // GCNConv
    k_mgemm<D_IN><<<ggrid, 256, 0, stream>>>(xb, Wlt, xwp, N_NODES);
    k_agg<0><<<agrid, 256, 0, stream>>>(xwp, nullptr, rp, cs, dinv, b_lin,
                                        nullptr, x0p, bns, N_NODES);

    // 5x GCN2Conv
    for (int i = 0; i < 5; ++i) {
        const uint4* zsrc = (i == 0) ? x0p : zp;
        if (i == 0)
            k_agg<1><<<agrid, 256, 0, stream>>>(zsrc, x0p, rp, cs, nullptr, nullptr, nullptr,
                                                hp, bns, N_NODES);
        else
            k_agg<2><<<agrid, 256, 0, stream>>>(zsrc, x0p, rp, cs, nullptr, nullptr, st,
                                                hp, bns, N_NODES);
        const unsigned short* W1 = Wt + (size_t)i * 128 * 128;
        if (i < 4) {
            k_lgemm<1><<<ggrid, 256, 0, stream>>>(hp, W1, zp, nullptr, bns, bns + 128, N_NODES);
            k_bn_fin<<<1, 128, 0, stream>>>(bns, bns + 128, gam + (size_t)i * 128,
                                            betp + (size_t)i * 128, st, N_NODES);
        } else {
            k_lgemm<2><<<ggrid, 256, 0, stream>>>(hp, W1, nullptr, out, nullptr, nullptr, N_NODES);
        }
    }
}

// Round 14
// 400.616 us; speedup vs baseline: 2.9856x; 2.9856x over previous
//
#include <hip/hip_runtime.h>
#include <math.h>

#define N_NODES 50000
#define N_EDGES 800000
#define D_IN 256
#define D_HID 128
#define ALPHA 0.1f
#define EPS 1e-5f

#define NBUCK 391   // ceil(50000/128)
#define EPB 4096    // edges per histogram/scatter block
#define NBLK 196    // ceil(800000/4096)

typedef __attribute__((ext_vector_type(8))) short bf16x8;
typedef __attribute__((ext_vector_type(4))) float f32x4;

static __device__ __forceinline__ unsigned short f2bf(float f) {
    unsigned int x = __float_as_uint(f);
    return (unsigned short)((x + 0x7fffu + ((x >> 16) & 1u)) >> 16);
}
static __device__ __forceinline__ float blo(unsigned int v) {
    return __uint_as_float(v << 16);
}
static __device__ __forceinline__ float bhi(unsigned int v) {
    return __uint_as_float(v & 0xffff0000u);
}

// ---------------- CSR build: hierarchical counting sort ----------------
__global__ __launch_bounds__(256) void k_hist(const int* __restrict__ dst,
                                              int* __restrict__ hist, int e) {
    __shared__ int h[NBUCK];
    int t = threadIdx.x;
    for (int i = t; i < NBUCK; i += 256) h[i] = 0;
    __syncthreads();
    int base = blockIdx.x * EPB;
    int lim = e - base;
    if (lim > EPB) lim = EPB;
    for (int i = t; i < lim; i += 256) atomicAdd(&h[dst[base + i] >> 7], 1);
    __syncthreads();
    for (int i = t; i < NBUCK; i += 256) hist[blockIdx.x * NBUCK + i] = h[i];
}

__global__ __launch_bounds__(256) void k_bkscan(const int* __restrict__ hist,
                                                int* __restrict__ offsT, int* __restrict__ btot) {
    __shared__ int sh[256];
    int b = blockIdx.x;
    int t = threadIdx.x;
    int v = (t < NBLK) ? hist[t * NBUCK + b] : 0;
    sh[t] = v;
    __syncthreads();
    for (int ofs = 1; ofs < 256; ofs <<= 1) {
        int y = (t >= ofs) ? sh[t - ofs] : 0;
        __syncthreads();
        sh[t] += y;
        __syncthreads();
    }
    if (t < NBLK) offsT[b * NBLK + t] = sh[t] - v;
    if (t == 255) btot[b] = sh[255];
}

__global__ __launch_bounds__(512) void k_bbase(const int* __restrict__ btot,
                                               int* __restrict__ bbase, int* __restrict__ rp) {
    __shared__ int sh[512];
    int t = threadIdx.x;
    int v = (t < NBUCK) ? btot[t] : 0;
    sh[t] = v;
    __syncthreads();
    for (int ofs = 1; ofs < 512; ofs <<= 1) {
        int y = (t >= ofs) ? sh[t - ofs] : 0;
        __syncthreads();
        sh[t] += y;
        __syncthreads();
    }
    if (t < NBUCK) bbase[t] = sh[t] - v;
    if (t == 0) rp[N_NODES] = N_EDGES;
}

__global__ __launch_bounds__(256) void k_scatter(const int* __restrict__ src,
                                                 const int* __restrict__ dst,
                                                 const int* __restrict__ offsT,
                                                 const int* __restrict__ bbase,
                                                 unsigned int* __restrict__ buck, int e) {
    __shared__ int h[NBUCK];
    int t = threadIdx.x;
    for (int i = t; i < NBUCK; i += 256) h[i] = 0;
    __syncthreads();
    int base = blockIdx.x * EPB;
    int lim = e - base;
    if (lim > EPB) lim = EPB;
    for (int i = t; i < lim; i += 256) {
        int d = dst[base + i];
        int s = src[base + i];
        int b = d >> 7;
        int lp = atomicAdd(&h[b], 1);
        int pos = bbase[b] + offsT[b * NBLK + blockIdx.x] + lp;
        buck[pos] = (unsigned int)s | ((unsigned int)(d & 127) << 16);
    }
}

// cs written as ushort (node ids < 65536)
__global__ __launch_bounds__(256) void k_csr(const unsigned int* __restrict__ buck,
                                             const int* __restrict__ bbase,
                                             const int* __restrict__ btot,
                                             int* __restrict__ rp, float* __restrict__ dinv,
                                             unsigned short* __restrict__ cs) {
    __shared__ int dcnt[128];
    __shared__ int doff[128];
    int b = blockIdx.x;
    int t = threadIdx.x;
    if (t < 128) dcnt[t] = 0;
    __syncthreads();
    int base = bbase[b];
    int tot = btot[b];
    for (int i = t; i < tot; i += 256) {
        unsigned int v = buck[base + i];
        atomicAdd(&dcnt[(v >> 16) & 127], 1);
    }
    __syncthreads();
    if (t < 128) doff[t] = dcnt[t];
    __syncthreads();
    for (int ofs = 1; ofs < 128; ofs <<= 1) {
        int y = 0;
        if (t < 128 && t >= ofs) y = doff[t - ofs];
        __syncthreads();
        if (t < 128) doff[t] += y;
        __syncthreads();
    }
    int gd0 = b << 7;
    if (t < 128) {
        int ex = doff[t] - dcnt[t];
        if (gd0 + t < N_NODES) {
            rp[gd0 + t] = base + ex;
            dinv[gd0 + t] = rsqrtf((float)(dcnt[t] + 1));
        }
        dcnt[t] = ex;
    }
    __syncthreads();
    for (int i = t; i < tot; i += 256) {
        unsigned int v = buck[base + i];
        int p = atomicAdd(&dcnt[(v >> 16) & 127], 1);
        cs[base + p] = (unsigned short)(v & 0xffffu);
    }
}

// ---------------- cast x to bf16 (streaming, full occupancy) ----------------
__global__ __launch_bounds__(256) void k_cast_x(const float4* __restrict__ x, ushort2* __restrict__ xb,
                                                int n4) {
    int i = blockIdx.x * 256 + threadIdx.x;
    if (i < n4) {
        float4 v = x[i];
        ushort2 a;
        a.x = f2bf(v.x); a.y = f2bf(v.y);
        ushort2 b;
        b.x = f2bf(v.z); b.y = f2bf(v.w);
        xb[i * 2] = a;
        xb[i * 2 + 1] = b;
    }
}

// ---------------- prep weights ----------------
__global__ __launch_bounds__(256) void k_prep_w(const float* __restrict__ W_lin,
                                                const float* __restrict__ W1s,
                                                unsigned short* __restrict__ Wlt,
                                                unsigned short* __restrict__ Wt) {
    int idx = blockIdx.x * 256 + threadIdx.x;
    if (idx < 128 * 256) {
        int c = idx >> 8, k = idx & 255;
        Wlt[idx] = f2bf(W_lin[k * 128 + c]);
    } else {
        int j = idx - 128 * 256;
        if (j < 5 * 128 * 128) {
            int l = j >> 14;
            int rem = j & 16383;
            int c = rem >> 7, k = rem & 127;
            float bet = logf(0.5f / (float)(l + 1) + 1.0f);
            float v = bet * W1s[l * 16384 + k * 128 + c];
            if (c == k) v += 1.0f - bet;
            Wt[j] = f2bf(v);
        }
    }
}

// ---------------- first GEMM (K=256): out bf16 row, PRE-SCALED by dinv[row] ----------------
template <int K>
__global__ __launch_bounds__(256) void k_mgemm(const unsigned short* __restrict__ A,
                                               const unsigned short* __restrict__ Bt,
                                               const float* __restrict__ dinv,
                                               unsigned short* __restrict__ outb, int M) {
    __shared__ short lds[2 * 128 * 136];
    short* As = lds;
    short* Bs = lds + 128 * 136;

    int t = threadIdx.x;
    int lane = t & 63;
    int wave = t >> 6;
    int wr = wave >> 1, wc = wave & 1;
    int row0 = blockIdx.x * 128;

    f32x4 acc[4][4];
#pragma unroll
    for (int m = 0; m < 4; ++m)
#pragma unroll
        for (int n = 0; n < 4; ++n) acc[m][n] = (f32x4){0.f, 0.f, 0.f, 0.f};

    int sr = t >> 1;
    int sh = t & 1;

    for (int k0 = 0; k0 < K; k0 += 128) {
        {
            int gr = row0 + sr;
            uint4 zero = {0, 0, 0, 0};
            const uint4* gp = (const uint4*)(A + (size_t)gr * K + k0 + sh * 64);
#pragma unroll
            for (int u = 0; u < 8; ++u) {
                uint4 v = (gr < M) ? gp[u] : zero;
                *(uint4*)(As + sr * 136 + sh * 64 + u * 8) = v;
            }
        }
        {
            const uint4* gp = (const uint4*)(Bt + (size_t)sr * K + k0 + sh * 64);
#pragma unroll
            for (int u = 0; u < 8; ++u) {
                *(uint4*)(Bs + sr * 136 + sh * 64 + u * 8) = gp[u];
            }
        }
        __syncthreads();

#pragma unroll
        for (int ks = 0; ks < 4; ++ks) {
            bf16x8 af[4], bfr[4];
#pragma unroll
            for (int m = 0; m < 4; ++m)
                af[m] = *(const bf16x8*)(As + (wr * 64 + m * 16 + (lane & 15)) * 136 + ks * 32 + (lane >> 4) * 8);
#pragma unroll
            for (int n = 0; n < 4; ++n)
                bfr[n] = *(const bf16x8*)(Bs + (wc * 64 + n * 16 + (lane & 15)) * 136 + ks * 32 + (lane >> 4) * 8);
#pragma unroll
            for (int m = 0; m < 4; ++m)
#pragma unroll
                for (int n = 0; n < 4; ++n)
                    acc[m][n] = __builtin_amdgcn_mfma_f32_16x16x32_bf16(af[m], bfr[n], acc[m][n], 0, 0, 0);
        }
        __syncthreads();
    }

    short* Z = lds;
#pragma unroll
    for (int m = 0; m < 4; ++m)
#pragma unroll
        for (int r = 0; r < 4; ++r) {
            int rl = wr * 64 + m * 16 + (lane >> 4) * 4 + r;
            int grow = row0 + rl;
            float dv = (grow < M) ? dinv[grow] : 0.f;
#pragma unroll
            for (int n = 0; n < 4; ++n) {
                int cl = wc * 64 + n * 16 + (lane & 15);
                Z[rl * 136 + cl] = (short)f2bf(acc[m][n][r] * dv);
            }
        }
    __syncthreads();
    int gr = row0 + sr;
    if (gr < M) {
#pragma unroll
        for (int u = 0; u < 8; ++u)
            *(uint4*)(outb + (size_t)gr * 128 + sh * 64 + u * 8) = *(uint4*)(Z + sr * 136 + sh * 64 + u * 8);
    }
}

// ---------------- layer GEMM (K=128): B in registers ----------------
// MODE 1: bf16 out + BN stats; MODE 2: f32 out
template <int MODE>
__global__ __launch_bounds__(256) void k_lgemm(const unsigned short* __restrict__ A,
                                               const unsigned short* __restrict__ Bt,
                                               unsigned short* __restrict__ outb,
                                               float* __restrict__ outf,
                                               float* __restrict__ bn_s, float* __restrict__ bn_q,
                                               int M) {
    __shared__ short As[128 * 136];
    int t = threadIdx.x;
    int lane = t & 63;
    int wave = t >> 6;
    int wr = wave >> 1, wc = wave & 1;
    int row0 = blockIdx.x * 128;

    bf16x8 bfr[4][4];
#pragma unroll
    for (int ks = 0; ks < 4; ++ks)
#pragma unroll
        for (int n = 0; n < 4; ++n)
            bfr[ks][n] = *(const bf16x8*)(Bt + (size_t)(wc * 64 + n * 16 + (lane & 15)) * 128 + ks * 32 + (lane >> 4) * 8);

    int sr = t >> 1, sh = t & 1;
    {
        int gr = row0 + sr;
        uint4 zero = {0, 0, 0, 0};
        const uint4* gp = (const uint4*)(A + (size_t)gr * 128 + sh * 64);
#pragma unroll
        for (int u = 0; u < 8; ++u) {
            uint4 v = (gr < M) ? gp[u] : zero;
            *(uint4*)(As + sr * 136 + sh * 64 + u * 8) = v;
        }
    }
    __syncthreads();

    f32x4 acc[4][4];
#pragma unroll
    for (int m = 0; m < 4; ++m)
#pragma unroll
        for (int n = 0; n < 4; ++n) acc[m][n] = (f32x4){0.f, 0.f, 0.f, 0.f};

#pragma unroll
    for (int ks = 0; ks < 4; ++ks) {
        bf16x8 af[4];
#pragma unroll
        for (int m = 0; m < 4; ++m)
            af[m] = *(const bf16x8*)(As + (wr * 64 + m * 16 + (lane & 15)) * 136 + ks * 32 + (lane >> 4) * 8);
#pragma unroll
        for (int m = 0; m < 4; ++m)
#pragma unroll
            for (int n = 0; n < 4; ++n)
                acc[m][n] = __builtin_amdgcn_mfma_f32_16x16x32_bf16(af[m], bfr[ks][n], acc[m][n], 0, 0, 0);
    }

    if (MODE == 1) {
        float sum[4] = {0.f, 0.f, 0.f, 0.f}, sq[4] = {0.f, 0.f, 0.f, 0.f};
#pragma unroll
        for (int n = 0; n < 4; ++n)
#pragma unroll
            for (int m = 0; m < 4; ++m)
#pragma unroll
                for (int r = 0; r < 4; ++r) {
                    float v = acc[m][n][r];
                    sum[n] += v;
                    sq[n] += v * v;
                }
#pragma unroll
        for (int n = 0; n < 4; ++n) {
            sum[n] += __shfl_xor(sum[n], 16);
            sum[n] += __shfl_xor(sum[n], 32);
            sq[n] += __shfl_xor(sq[n], 16);
            sq[n] += __shfl_xor(sq[n], 32);
        }
        if (lane < 16) {
#pragma unroll
            for (int n = 0; n < 4; ++n) {
                int col = wc * 64 + n * 16 + lane;
                atomicAdd(&bn_s[col], sum[n]);
                atomicAdd(&bn_q[col], sq[n]);
            }
        }
    }

    if (MODE == 2) {
#pragma unroll
        for (int m = 0; m < 4; ++m)
#pragma unroll
            for (int n = 0; n < 4; ++n)
#pragma unroll
                for (int r = 0; r < 4; ++r) {
                    int gr = row0 + wr * 64 + m * 16 + (lane >> 4) * 4 + r;
                    int cl = wc * 64 + n * 16 + (lane & 15);
                    if (gr < M) outf[(size_t)gr * 128 + cl] = acc[m][n][r];
                }
    } else {
        __syncthreads();
        short* Z = As;
#pragma unroll
        for (int m = 0; m < 4; ++m)
#pragma unroll
            for (int n = 0; n < 4; ++n)
#pragma unroll
                for (int r = 0; r < 4; ++r) {
                    int rl = wr * 64 + m * 16 + (lane >> 4) * 4 + r;
                    int cl = wc * 64 + n * 16 + (lane & 15);
                    Z[rl * 136 + cl] = (short)f2bf(acc[m][n][r]);
                }
        __syncthreads();
        int gr = row0 + sr;
        if (gr < M) {
#pragma unroll
            for (int u = 0; u < 8; ++u)
                *(uint4*)(outb + (size_t)gr * 128 + sh * 64 + u * 8) = *(uint4*)(Z + sr * 136 + sh * 64 + u * 8);
        }
    }
}

// ---------------- aggregation: one wave per node, shfl-broadcast, unroll 8 ----------------
// MODE 0: GCNConv (rows pre-scaled by dinv[src]; h = dinv[d]*(sum+self) + bias)
// MODE 1: GCN2 plain sum; MODE 2: GCN2 + fused BN/ReLU
template <int MODE>
__global__ __launch_bounds__(256) void k_agg(const unsigned int* __restrict__ src,
                                             const unsigned int* __restrict__ x0b,
                                             const int* __restrict__ rp,
                                             const unsigned short* __restrict__ cs,
                                             const float* __restrict__ dinv,
                                             const float* __restrict__ b_lin,
                                             const float* __restrict__ st,
                                             unsigned int* __restrict__ dst,
                                             float* __restrict__ bns, int n) {
    if (blockIdx.x == 0) bns[threadIdx.x] = 0.f;  // zero BN stats for the following GEMM

    int wid = (blockIdx.x * 256 + threadIdx.x) >> 6;
    int lane = threadIdx.x & 63;
    if (wid >= n) return;

    int start = __builtin_amdgcn_readfirstlane(rp[wid]);
    int end = __builtin_amdgcn_readfirstlane(rp[wid + 1]);

    float2 sc = {0.f, 0.f}, tc = {0.f, 0.f};
    if (MODE == 2) {
        sc = ((const float2*)st)[lane];
        tc = ((const float2*)st)[64 + lane];
    }

    float ax = 0.f, ay = 0.f;

    for (int base = start; base < end; base += 64) {
        int cnt = end - base;
        if (cnt > 64) cnt = 64;
        int myi = (int)cs[base + ((lane < cnt) ? lane : (cnt - 1))];

        int j = 0;
        for (; j + 7 < cnt; j += 8) {
            int s0 = __shfl(myi, j), s1 = __shfl(myi, j + 1);
            int s2 = __shfl(myi, j + 2), s3 = __shfl(myi, j + 3);
            int s4 = __shfl(myi, j + 4), s5 = __shfl(myi, j + 5);
            int s6 = __shfl(myi, j + 6), s7 = __shfl(myi, j + 7);
            unsigned int v0 = src[(size_t)s0 * 64 + lane];
            unsigned int v1 = src[(size_t)s1 * 64 + lane];
            unsigned int v2 = src[(size_t)s2 * 64 + lane];
            unsigned int v3 = src[(size_t)s3 * 64 + lane];
            unsigned int v4 = src[(size_t)s4 * 64 + lane];
            unsigned int v5 = src[(size_t)s5 * 64 + lane];
            unsigned int v6 = src[(size_t)s6 * 64 + lane];
            unsigned int v7 = src[(size_t)s7 * 64 + lane];
            if (MODE == 2) {
                ax += fmaxf(fmaf(sc.x, blo(v0), tc.x), 0.f) + fmaxf(fmaf(sc.x, blo(v1), tc.x), 0.f) +
                      fmaxf(fmaf(sc.x, blo(v2), tc.x), 0.f) + fmaxf(fmaf(sc.x, blo(v3), tc.x), 0.f) +
                      fmaxf(fmaf(sc.x, blo(v4), tc.x), 0.f) + fmaxf(fmaf(sc.x, blo(v5), tc.x), 0.f) +
                      fmaxf(fmaf(sc.x, blo(v6), tc.x), 0.f) + fmaxf(fmaf(sc.x, blo(v7), tc.x), 0.f);
                ay += fmaxf(fmaf(sc.y, bhi(v0), tc.y), 0.f) + fmaxf(fmaf(sc.y, bhi(v1), tc.y), 0.f) +
                      fmaxf(fmaf(sc.y, bhi(v2), tc.y), 0.f) + fmaxf(fmaf(sc.y, bhi(v3), tc.y), 0.f) +
                      fmaxf(fmaf(sc.y, bhi(v4), tc.y), 0.f) + fmaxf(fmaf(sc.y, bhi(v5), tc.y), 0.f) +
                      fmaxf(fmaf(sc.y, bhi(v6), tc.y), 0.f) + fmaxf(fmaf(sc.y, bhi(v7), tc.y), 0.f);
            } else {
                ax += blo(v0) + blo(v1) + blo(v2) + blo(v3) + blo(v4) + blo(v5) + blo(v6) + blo(v7);
                ay += bhi(v0) + bhi(v1) + bhi(v2) + bhi(v3) + bhi(v4) + bhi(v5) + bhi(v6) + bhi(v7);
            }
        }
        for (; j < cnt; ++j) {
            int s0 = __shfl(myi, j);
            unsigned int v0 = src[(size_t)s0 * 64 + lane];
            if (MODE == 2) {
                ax += fmaxf(fmaf(sc.x, blo(v0), tc.x), 0.f);
                ay += fmaxf(fmaf(sc.y, bhi(v0), tc.y), 0.f);
            } else {
                ax += blo(v0);
                ay += bhi(v0);
            }
        }
    }

    if (MODE == 0) {
        unsigned int vs = src[(size_t)wid * 64 + lane];  // pre-scaled self row
        float dn = dinv[wid];
        float2 bb = ((const float2*)b_lin)[lane];
        ax = (ax + blo(vs)) * dn + bb.x;
        ay = (ay + bhi(vs)) * dn + bb.y;
    } else {
        unsigned int xv = x0b[(size_t)wid * 64 + lane];
        ax = fmaf(ALPHA, blo(xv), (1.0f - ALPHA) * ax);
        ay = fmaf(ALPHA, bhi(xv), (1.0f - ALPHA) * ay);
    }
    dst[(size_t)wid * 64 + lane] = (unsigned int)f2bf(ax) | ((unsigned int)f2bf(ay) << 16);
}

// ---------------- BN finalize ----------------
__global__ void k_bn_fin(const float* __restrict__ bn_s, const float* __restrict__ bn_q,
                         const float* __restrict__ gamma, const float* __restrict__ betap,
                         float* __restrict__ st, int n) {
    int c = threadIdx.x;
    float inv_n = 1.0f / (float)n;
    float mu = bn_s[c] * inv_n;
    float var = bn_q[c] * inv_n - mu * mu;
    var = fmaxf(var, 0.f);
    float s = gamma[c] * rsqrtf(var + EPS);
    st[c] = s;
    st[128 + c] = betap[c] - mu * s;
}

extern "C" void kernel_launch(void* const* d_in, const int* in_sizes, int n_in,
                              void* d_out, int out_size, void* d_ws, size_t ws_size,
                              hipStream_t stream) {
    const float* x = (const float*)d_in[0];
    const int* ei = (const int*)d_in[1];
    const float* W_lin = (const float*)d_in[2];
    const float* b_lin = (const float*)d_in[3];
    const float* W1s = (const float*)d_in[4];
    const float* gam = (const float*)d_in[5];
    const float* betp = (const float*)d_in[6];
    float* out = (float*)d_out;

    char* ws = (char*)d_ws;
    size_t off = 0;
    auto alloc = [&](size_t b) { size_t p = off; off = (off + b + 255) & ~(size_t)255; return p; };
    int* rp = (int*)(ws + alloc((size_t)(N_NODES + 1) * 4));
    unsigned short* cs = (unsigned short*)(ws + alloc((size_t)N_EDGES * 2));
    float* dinv = (float*)(ws + alloc((size_t)N_NODES * 4));
    int* hist = (int*)(ws + alloc((size_t)NBLK * NBUCK * 4));
    int* offsT = (int*)(ws + alloc((size_t)NBUCK * NBLK * 4));
    int* btot = (int*)(ws + alloc((size_t)NBUCK * 4));
    int* bbase = (int*)(ws + alloc((size_t)NBUCK * 4));
    unsigned int* buck = (unsigned int*)(ws + alloc((size_t)N_EDGES * 4));
    unsigned short* xb = (unsigned short*)(ws + alloc((size_t)N_NODES * D_IN * 2));
    unsigned short* xwb = (unsigned short*)(ws + alloc((size_t)N_NODES * D_HID * 2));
    unsigned short* x0b = (unsigned short*)(ws + alloc((size_t)N_NODES * D_HID * 2));
    unsigned short* zb = (unsigned short*)(ws + alloc((size_t)N_NODES * D_HID * 2));
    unsigned short* hb = (unsigned short*)(ws + alloc((size_t)N_NODES * D_HID * 2));
    unsigned short* Wlt = (unsigned short*)(ws + alloc((size_t)128 * 256 * 2));
    unsigned short* Wt = (unsigned short*)(ws + alloc((size_t)5 * 128 * 128 * 2));
    float* bns = (float*)(ws + alloc(256 * 4));
    float* st = (float*)(ws + alloc(256 * 4));

    const int ggrid = (N_NODES + 127) / 128;  // 391
    const int agrid = (N_NODES + 3) / 4;      // 12500 (4 waves/block, 1 node/wave)

    // CSR build (counting sort, coalesced writes)
    k_hist<<<NBLK, 256, 0, stream>>>(ei + N_EDGES, hist, N_EDGES);
    k_bkscan<<<NBUCK, 256, 0, stream>>>(hist, offsT, btot);
    k_bbase<<<1, 512, 0, stream>>>(btot, bbase, rp);
    k_scatter<<<NBLK, 256, 0, stream>>>(ei, ei + N_EDGES, offsT, bbase, buck, N_EDGES);
    k_csr<<<NBUCK, 256, 0, stream>>>(buck, bbase, btot, rp, dinv, cs);

    k_cast_x<<<(N_NODES * D_IN / 4 + 255) / 256, 256, 0, stream>>>((const float4*)x, (ushort2*)xb,
                                                                   N_NODES * D_IN / 4);
    k_prep_w<<<(128 * 256 + 5 * 128 * 128 + 255) / 256, 256, 0, stream>>>(W_lin, W1s, Wlt, Wt);

    // GCNConv (xw rows pre-scaled by dinv[row] in epilogue)
    k_mgemm<D_IN><<<ggrid, 256, 0, stream>>>(xb, Wlt, dinv, xwb, N_NODES);
    k_agg<0><<<agrid, 256, 0, stream>>>((const unsigned int*)xwb, nullptr, rp, cs, dinv, b_lin,
                                        nullptr, (unsigned int*)x0b, bns, N_NODES);

    // 5x GCN2Conv
    for (int i = 0; i < 5; ++i) {
        const unsigned short* zsrc = (i == 0) ? x0b : zb;
        if (i == 0)
            k_agg<1><<<agrid, 256, 0, stream>>>((const unsigned int*)zsrc, (const unsigned int*)x0b,
                                                rp, cs, nullptr, nullptr, nullptr,
                                                (unsigned int*)hb, bns, N_NODES);
        else
            k_agg<2><<<agrid, 256, 0, stream>>>((const unsigned int*)zsrc, (const unsigned int*)x0b,
                                                rp, cs, nullptr, nullptr, st,
                                                (unsigned int*)hb, bns, N_NODES);
        const unsigned short* W1 = Wt + (size_t)i * 128 * 128;
        if (i < 4) {
            k_lgemm<1><<<ggrid, 256, 0, stream>>>(hb, W1, zb, nullptr, bns, bns + 128, N_NODES);
            k_bn_fin<<<1, 128, 0, stream>>>(bns, bns + 128, gam + (size_t)i * 128,
                                            betp + (size_t)i * 128, st, N_NODES);
        } else {
            k_lgemm<2><<<ggrid, 256, 0, stream>>>(hb, W1, nullptr, out, nullptr, nullptr, N_NODES);
        }
    }
}